// Round 10
// baseline (453.922 us; speedup 1.0000x reference)
//
#include <hip/hip_runtime.h>
#include <hip/hip_bf16.h>

typedef __bf16 bf16x8 __attribute__((ext_vector_type(8)));
typedef float  f32x4  __attribute__((ext_vector_type(4)));

constexpr int   Bb   = 2;
constexpr int   Slen = 2048;
constexpr int   Hdim = 2048;
constexpr int   NHn  = 16;
constexpr int   HDd  = 128;
constexpr float QSCALE = 0.08838834764831845f; // 1/sqrt(128)
constexpr float NEG    = -1e30f;

// async global->LDS, 16B per lane; LDS dest = wave-uniform base + lane*16 (m97 pattern)
__device__ __forceinline__ void gld16(const __bf16* g, __bf16* l) {
    __builtin_amdgcn_global_load_lds(
        (__attribute__((address_space(1))) void*)(uintptr_t)(const void*)g,
        (__attribute__((address_space(3))) void*)l, 16, 0, 0);
}

// ---------------- fp32 -> bf16 bulk convert (vectorized) ----------------
__global__ __launch_bounds__(256) void cvt_bf16(const float* __restrict__ in,
                                                __bf16* __restrict__ out) {
    const size_t i = (size_t)(blockIdx.x * 256 + threadIdx.x) * 8;
    f32x4 a = *(const f32x4*)(in + i), b = *(const f32x4*)(in + i + 4);
    bf16x8 r;
    r[0] = (__bf16)a[0]; r[1] = (__bf16)a[1]; r[2] = (__bf16)a[2]; r[3] = (__bf16)a[3];
    r[4] = (__bf16)b[0]; r[5] = (__bf16)b[1]; r[6] = (__bf16)b[2]; r[7] = (__bf16)b[3];
    *(bf16x8*)(out + i) = r;
}

// ---------------- convert+transpose: fp32 [R][C] -> bf16 [C][R] ----------------
__global__ __launch_bounds__(256) void transpose_cvt(const float* __restrict__ in,
                                                     __bf16* __restrict__ out,
                                                     int R, int C) {
    __shared__ float t[64][65];
    const int c0 = blockIdx.x * 64, r0 = blockIdx.y * 64;
    const int tx = threadIdx.x & 63, ty = threadIdx.x >> 6;
#pragma unroll
    for (int i = 0; i < 16; ++i) {
        int r = i * 4 + ty;
        t[r][tx] = in[(size_t)(r0 + r) * C + c0 + tx];
    }
    __syncthreads();
#pragma unroll
    for (int i = 0; i < 16; ++i) {
        int r = i * 4 + ty;
        out[(size_t)(c0 + r) * R + r0 + tx] = (__bf16)t[tx][r];
    }
}

// ============================================================================
// 256x256xBK64 8-phase GEMM — FROZEN (clock canary): 152.9-155.1 us x4 at
// normal clocks; 194 on a slow container (all rate counters scale together).
// ============================================================================

#define BAR    __builtin_amdgcn_s_barrier()
#define LGKM0  asm volatile("s_waitcnt lgkmcnt(0)" ::: "memory")
#define VMC(n) asm volatile("s_waitcnt vmcnt(" #n ")" ::: "memory")
#define SCHED0 __builtin_amdgcn_sched_barrier(0)

#define STAGE(op, half, tt)                                                          \
  do {                                                                               \
    const int tt_ = (tt);                                                            \
    if (tt_ < NT) {                                                                  \
      __bf16* dst_ = lds + ((tt_ & 1) << 15) + ((op) << 14) + ((half) << 13);        \
      const __bf16* src_ = (op) ? Bt : A;                                            \
      const int rb_ = (op) ? n0 : m0;                                               \
      const int k0_ = tt_ << 6;                                                      \
      _Pragma("unroll")                                                              \
      for (int i_ = 0; i_ < 2; ++i_) {                                               \
        const int c_  = (i_ << 9) + tid;                                             \
        const int rl_ = c_ >> 3;                                                     \
        const int grow_ = rb_ + ((op) ? (((rl_ >> 5) << 6) + ((half) << 5) + (rl_ & 31)) \
                                      : (((rl_ >> 6) << 7) + ((half) << 6) + (rl_ & 63))); \
        const int gk_ = k0_ + (((c_ & 7) ^ (rl_ & 7)) << 3);                         \
        gld16(src_ + (size_t)grow_ * Kdim + gk_, dst_ + (c_ << 3));                  \
      }                                                                              \
    }                                                                                \
  } while (0)

#define LDA(bufv, mh)                                                                \
  do {                                                                               \
    const __bf16* Ab_ = lds + ((bufv) << 15) + ((mh) << 13) + (wg << 12) + (l16 << 6); \
    _Pragma("unroll")                                                                \
    for (int q_ = 0; q_ < 4; ++q_)                                                   \
      _Pragma("unroll")                                                              \
      for (int kk_ = 0; kk_ < 2; ++kk_)                                              \
        af[q_][kk_] = *(const bf16x8*)(Ab_ + (q_ << 10) +                            \
                        ((((kk_ << 2) + quad) ^ (l16 & 7)) << 3));                   \
  } while (0)

#define LDB(bufv, nh)                                                                \
  do {                                                                               \
    const __bf16* Bb_ = lds + ((bufv) << 15) + 16384 + ((nh) << 13) + (gn << 11) + (l16 << 6); \
    _Pragma("unroll")                                                                \
    for (int q_ = 0; q_ < 2; ++q_)                                                   \
      _Pragma("unroll")                                                              \
      for (int kk_ = 0; kk_ < 2; ++kk_)                                              \
        bfr[((nh) << 1) + q_][kk_] = *(const bf16x8*)(Bb_ + (q_ << 10) +             \
                        ((((kk_ << 2) + quad) ^ (l16 & 7)) << 3));                   \
  } while (0)

#define MM(mh, nh)                                                                   \
  do {                                                                               \
    _Pragma("unroll")                                                                \
    for (int q_ = 0; q_ < 4; ++q_)                                                   \
      _Pragma("unroll")                                                              \
      for (int n_ = 0; n_ < 2; ++n_)                                                 \
        _Pragma("unroll")                                                            \
        for (int kk_ = 0; kk_ < 2; ++kk_)                                            \
          acc[((mh) << 2) + q_][((nh) << 1) + n_] =                                  \
            __builtin_amdgcn_mfma_f32_16x16x32_bf16(                                 \
              af[q_][kk_], bfr[((nh) << 1) + n_][kk_],                               \
              acc[((mh) << 2) + q_][((nh) << 1) + n_], 0, 0, 0);                     \
  } while (0)

// QKV epilogue -> scatter Q (scaled), K row-major, V transposed
__global__ __launch_bounds__(512, 2) void gemm8(
    const __bf16* __restrict__ A, const __bf16* __restrict__ Bt,
    const float* __restrict__ bias, int Kdim, int Ndim,
    __bf16* __restrict__ Qo, __bf16* __restrict__ Ko, __bf16* __restrict__ Vto) {
    __shared__ __bf16 lds[65536];  // 128 KiB: [buf][A/B][half][...]
    const int tid  = threadIdx.x;
    const int lane = tid & 63, wave = tid >> 6;
    const int quad = lane >> 4, l16 = lane & 15;
    const int wg = wave >> 2;   // M wave-group (0/1)
    const int gn = wave & 3;    // N wave-group
    const int m0 = blockIdx.y * 256, n0 = blockIdx.x * 256;
    const int NT = Kdim >> 6;

    f32x4  acc[8][4] = {};
    bf16x8 af[4][2];
    bf16x8 bfr[4][2];

    STAGE(0, 0, 0); STAGE(1, 0, 0); STAGE(1, 1, 0); STAGE(0, 1, 0);
    STAGE(0, 0, 1); STAGE(1, 0, 1); STAGE(1, 1, 1);
    VMC(6);
    BAR;

    for (int t = 0; t < NT; ++t) {
        const int cb = t & 1;
        LDA(cb, 0); LDB(cb, 0);
        STAGE(0, 1, t + 1);
        BAR; LGKM0;
        __builtin_amdgcn_s_setprio(1); MM(0, 0); __builtin_amdgcn_s_setprio(0);
        BAR;
        LDB(cb, 1);
        STAGE(0, 0, t + 2);
        BAR; LGKM0;
        __builtin_amdgcn_s_setprio(1); MM(0, 1); __builtin_amdgcn_s_setprio(0);
        BAR;
        LDA(cb, 1);
        STAGE(1, 0, t + 2);
        BAR; LGKM0;
        __builtin_amdgcn_s_setprio(1); MM(1, 1); __builtin_amdgcn_s_setprio(0);
        BAR;
        STAGE(1, 1, t + 2);
        if (t < NT - 2) { VMC(6); } else { VMC(0); }
        BAR;
        __builtin_amdgcn_s_setprio(1); MM(1, 0); __builtin_amdgcn_s_setprio(0);
        BAR;
    }

#pragma unroll
    for (int mi = 0; mi < 8; ++mi) {
#pragma unroll
        for (int r = 0; r < 4; ++r) {
            const int m = m0 + wg * 128 + (mi >> 2) * 64 + (mi & 3) * 16 + quad * 4 + r;
            const int b = m >> 11, s = m & 2047;
#pragma unroll
            for (int ni = 0; ni < 4; ++ni) {
                const int cc = n0 + gn * 64 + (ni >> 1) * 32 + (ni & 1) * 16 + l16;
                float val = acc[mi][ni][r] + bias[cc];
                const int h = cc / 384;
                const int rr = cc - h * 384;
                const size_t hb = ((size_t)(b * NHn + h) * Slen + s);
                if (rr < 128)
                    Qo[hb * HDd + rr] = (__bf16)(val * QSCALE);
                else if (rr < 256)
                    Ko[hb * HDd + (rr - 128)] = (__bf16)val;
                else
                    Vto[((size_t)(b * NHn + h) * HDd + (rr - 256)) * Slen + s] = (__bf16)val;
            }
        }
    }
}

// ============================================================================
// Output-projection GEMM — FROZEN (measured-good): BM=128 x BN=256 x BK=64,
// 8 waves of 64x64, 4-phase counted-vmcnt, no pins, 256 blocks.
// ============================================================================

#define STA1(half, tt)                                                               \
  do {                                                                               \
    const int tt_ = (tt);                                                            \
    if (tt_ < NT) {                                                                  \
      __bf16* dst_ = lds2 + ((tt_ & 1) ? 24576 : 0) + ((half) << 12);                \
      const int k0_ = tt_ << 6;                                                      \
      const int c_  = tid;                       /* 0..511, 1 chunk each */          \
      const int rl_ = c_ >> 3;                   /* 0..63 local A-half row */        \
      const int grow_ = m0 + ((rl_ >> 5) << 6) + ((half) << 5) + (rl_ & 31);         \
      const int gk_ = k0_ + (((c_ & 7) ^ (rl_ & 7)) << 3);                           \
      gld16(A + (size_t)grow_ * Kdim + gk_, dst_ + (c_ << 3));                       \
    }                                                                                \
  } while (0)

#define STB1(half, tt)                                                               \
  do {                                                                               \
    const int tt_ = (tt);                                                            \
    if (tt_ < NT) {                                                                  \
      __bf16* dst_ = lds2 + ((tt_ & 1) ? 24576 : 0) + 8192 + ((half) << 13);         \
      const int k0_ = tt_ << 6;                                                      \
      _Pragma("unroll")                                                              \
      for (int i_ = 0; i_ < 2; ++i_) {                                               \
        const int c_  = (i_ << 9) + tid;         /* 0..1023 */                       \
        const int rl_ = c_ >> 3;                 /* 0..127 local B-half row */       \
        const int grow_ = n0 + ((rl_ >> 5) << 6) + ((half) << 5) + (rl_ & 31);       \
        const int gk_ = k0_ + (((c_ & 7) ^ (rl_ & 7)) << 3);                         \
        gld16(Bt + (size_t)grow_ * Kdim + gk_, dst_ + (c_ << 3));                    \
      }                                                                              \
    }                                                                                \
  } while (0)

#define LDA1(bufv, h)                                                                \
  do {                                                                               \
    const __bf16* Ab_ = lds2 + ((bufv) ? 24576 : 0) + ((h) << 12) + (wg << 11) + (l16 << 6); \
    _Pragma("unroll")                                                                \
    for (int q_ = 0; q_ < 2; ++q_)                                                   \
      _Pragma("unroll")                                                              \
      for (int kk_ = 0; kk_ < 2; ++kk_)                                              \
        af1[q_][kk_] = *(const bf16x8*)(Ab_ + (q_ << 10) +                           \
                        ((((kk_ << 2) + quad) ^ (l16 & 7)) << 3));                   \
  } while (0)

#define LDB1(bufv, nh)                                                               \
  do {                                                                               \
    const __bf16* Bb_ = lds2 + ((bufv) ? 24576 : 0) + 8192 + ((nh) << 13) + (gn << 11) + (l16 << 6); \
    _Pragma("unroll")                                                                \
    for (int q_ = 0; q_ < 2; ++q_)                                                   \
      _Pragma("unroll")                                                              \
      for (int kk_ = 0; kk_ < 2; ++kk_)                                              \
        bfr1[((nh) << 1) + q_][kk_] = *(const bf16x8*)(Bb_ + (q_ << 10) +            \
                        ((((kk_ << 2) + quad) ^ (l16 & 7)) << 3));                   \
  } while (0)

#define MM1(h, nh)                                                                   \
  do {                                                                               \
    _Pragma("unroll")                                                                \
    for (int q_ = 0; q_ < 2; ++q_)                                                   \
      _Pragma("unroll")                                                              \
      for (int n_ = 0; n_ < 2; ++n_)                                                 \
        _Pragma("unroll")                                                            \
        for (int kk_ = 0; kk_ < 2; ++kk_)                                            \
          acc1[((h) << 1) + q_][((nh) << 1) + n_] =                                  \
            __builtin_amdgcn_mfma_f32_16x16x32_bf16(                                 \
              af1[q_][kk_], bfr1[((nh) << 1) + n_][kk_],                             \
              acc1[((h) << 1) + q_][((nh) << 1) + n_], 0, 0, 0);                     \
  } while (0)

__global__ __launch_bounds__(512, 2) void gemm_bm128(
    const __bf16* __restrict__ A, const __bf16* __restrict__ Bt,
    const float* __restrict__ bias, int Kdim, int Ndim,
    float* __restrict__ Cout) {
    __shared__ __bf16 lds2[49152];  // 96 KiB: 2 x (A 8192 + B 16384 elems)
    const int tid  = threadIdx.x;
    const int lane = tid & 63, wave = tid >> 6;
    const int quad = lane >> 4, l16 = lane & 15;
    const int wg = wave >> 2;   // M wave-group (0/1) -> rows wg*64..+63
    const int gn = wave & 3;    // N wave-group      -> cols gn*64..+63
    const int m0 = blockIdx.y * 128, n0 = blockIdx.x * 256;
    const int NT = Kdim >> 6;

    f32x4  acc1[4][4] = {};
    bf16x8 af1[2][2];
    bf16x8 bfr1[4][2];

    STA1(0, 0); STB1(0, 0); STB1(1, 0); STA1(1, 0);
    STA1(0, 1); STB1(0, 1); STB1(1, 1);
    VMC(5);
    BAR;

    for (int t = 0; t < NT; ++t) {
        const int cb = t & 1;
        LDA1(cb, 0); LDB1(cb, 0);
        STA1(1, t + 1);
        BAR; LGKM0;
        __builtin_amdgcn_s_setprio(1); MM1(0, 0); __builtin_amdgcn_s_setprio(0);
        BAR;
        LDB1(cb, 1);
        STA1(0, t + 2);
        BAR; LGKM0;
        __builtin_amdgcn_s_setprio(1); MM1(0, 1); __builtin_amdgcn_s_setprio(0);
        BAR;
        LDA1(cb, 1);
        STB1(0, t + 2);
        BAR; LGKM0;
        __builtin_amdgcn_s_setprio(1); MM1(1, 1); __builtin_amdgcn_s_setprio(0);
        BAR;
        STB1(1, t + 2);
        if (t < NT - 2) { VMC(5); } else { VMC(0); }
        BAR;
        __builtin_amdgcn_s_setprio(1); MM1(1, 0); __builtin_amdgcn_s_setprio(0);
        BAR;
    }

#pragma unroll
    for (int mi = 0; mi < 4; ++mi) {
#pragma unroll
        for (int r = 0; r < 4; ++r) {
            const int m = m0 + wg * 64 + (mi >> 1) * 32 + (mi & 1) * 16 + quad * 4 + r;
#pragma unroll
            for (int ni = 0; ni < 4; ++ni) {
                const int cc = n0 + gn * 64 + (ni >> 1) * 32 + (ni & 1) * 16 + l16;
                Cout[(size_t)m * Ndim + cc] = acc1[mi][ni][r] + bias[cc];
            }
        }
    }
}

// ============================================================================
// flash attention — ROUND-8 EXACT REVERT (best-known config, ~206 us-normalized
// for attn+bm128+fixed): r3/r4 block map, unconditional-rescale online softmax,
// SCHED0 pins retained. r9's bundled T13+pin-removal cost ~+89 us (suspected
// divergent-branch register-pressure spill, rule #20) -> reverted.
// ============================================================================

#define ASTAGE(tt)                                                                   \
  do {                                                                               \
    const int tt_ = (tt);                                                            \
    if (tt_ < ktiles) {                                                              \
      const int kb_ = tt_ << 6;                                                      \
      __bf16* kd_ = Ks + ((tt_ & 1) << 13);                                          \
      __bf16* vd_ = Vs + ((tt_ & 1) << 13);                                          \
      _Pragma("unroll")                                                              \
      for (int i_ = 0; i_ < 2; ++i_) {                                               \
        const int c_ = (i_ << 9) + tid;              /* 0..1023 chunk id */          \
        const int kr_ = c_ >> 4, kc_ = c_ & 15;      /* K: row=key, 16 chunks */     \
        gld16(Kb + (size_t)(kb_ + kr_) * HDd + ((kc_ ^ (kr_ & 7)) << 3),             \
              kd_ + (c_ << 3));                                                      \
        const int vr_ = c_ >> 3, vc_ = c_ & 7;       /* V: row=d, 8 chunks */        \
        gld16(Vb + (size_t)vr_ * Slen + kb_ + ((vc_ ^ (vr_ & 7)) << 3),              \
              vd_ + (c_ << 3));                                                      \
      }                                                                              \
    }                                                                                \
  } while (0)

__global__ __launch_bounds__(512, 4) void attn_k(const __bf16* __restrict__ Q,
                                                 const __bf16* __restrict__ Kmat,
                                                 const __bf16* __restrict__ Vt,
                                                 __bf16* __restrict__ ctx) {
    __shared__ __bf16 Ks[2 * 64 * 128];   // 32KB dbuf [key][d]
    __shared__ __bf16 Vs[2 * 128 * 64];   // 32KB dbuf [d][key]
    __shared__ __bf16 Ps[8 * 16 * 64];    // 16KB wave-private P, swizzled
    const int tid = threadIdx.x, lane = tid & 63, wave = tid >> 6;
    const int quad = lane >> 4, l16 = lane & 15;

    // round-3/4 map: 512 blocks, chunk 64 = 4 consecutive bh per XCD;
    // within chunk qx ascends -> qt = 15-qx (heavy blocks first).
    const int flat = blockIdx.x + (blockIdx.y << 4);   // gridDim.x == 16
    const int nf   = (flat & 7) * 64 + (flat >> 3);
    const int qx   = nf & 15, bh = nf >> 4;
    const int qt   = 15 - qx;                          // heavy blocks first
    const int b = bh >> 4, h = bh & 15;
    const __bf16* Qb = Q    + (size_t)bh * Slen * HDd;
    const __bf16* Kb = Kmat + (size_t)bh * Slen * HDd;
    const __bf16* Vb = Vt   + (size_t)bh * HDd * Slen;
    const int q0 = qt * 128;
    const int qa = q0 + wave * 16 + l16;       // A-frag row
    const int qc = q0 + wave * 16 + quad * 4;  // C-layout base row
    const int swz = (l16 & 7);

    bf16x8 qf[4];
#pragma unroll
    for (int kk = 0; kk < 4; ++kk)
        qf[kk] = *(const bf16x8*)(Qb + (size_t)qa * HDd + kk * 32 + quad * 8);

    f32x4 accO[8] = {};
    float m_i[4] = {NEG, NEG, NEG, NEG};
    float l_i[4] = {0.f, 0.f, 0.f, 0.f};
    __bf16* Pw = Ps + wave * 1024;  // [16 rows][64 cols], chunk-swizzled

    const int ktiles = 2 * qt + 2;  // 64-key tiles covering keys 0..q0+127

    ASTAGE(0);
    for (int kt = 0; kt < ktiles; ++kt) {
        const int cur = kt & 1;
        const int kb0 = kt * 64;
        ASTAGE(kt + 1);                       // prefetch next tile into ~cur
        SCHED0;
        if (kt + 1 < ktiles) { VMC(4); } else { VMC(0); }
        BAR;                                  // buf(cur) staged by ALL waves

        const __bf16* Kt = Ks + (cur << 13);
        const __bf16* Vc = Vs + (cur << 13);

        // ---- QK^T: 16 MFMA ----
        f32x4 sc[4];
        __builtin_amdgcn_s_setprio(1);
#pragma unroll
        for (int nk = 0; nk < 4; ++nk) {
            f32x4 z = {0.f, 0.f, 0.f, 0.f};
#pragma unroll
            for (int kk = 0; kk < 4; ++kk) {
                bf16x8 kf = *(const bf16x8*)(Kt + (nk * 16 + l16) * 128 +
                                             (((kk << 2) + quad) ^ swz) * 8);
                z = __builtin_amdgcn_mfma_f32_16x16x32_bf16(qf[kk], kf, z, 0, 0, 0);
            }
            sc[nk] = z;
        }
        __builtin_amdgcn_s_setprio(0);
        if (kt >= ktiles - 2) {  // diagonal-range tiles: causal mask
#pragma unroll
            for (int nk = 0; nk < 4; ++nk) {
                const int kg = kb0 + nk * 16 + l16;
#pragma unroll
                for (int r = 0; r < 4; ++r)
                    if (kg > qc + r) sc[nk][r] = NEG;
            }
        }
        // ---- online softmax across the quad's 16 lanes ----
#pragma unroll
        for (int r = 0; r < 4; ++r) {
            float mm = fmaxf(fmaxf(sc[0][r], sc[1][r]), fmaxf(sc[2][r], sc[3][r]));
            mm = fmaxf(mm, __shfl_xor(mm, 1));
            mm = fmaxf(mm, __shfl_xor(mm, 2));
            mm = fmaxf(mm, __shfl_xor(mm, 4));
            mm = fmaxf(mm, __shfl_xor(mm, 8));
            const float mnew = fmaxf(m_i[r], mm);
            const float alpha = __expf(m_i[r] - mnew);
            float ls = 0.f;
#pragma unroll
            for (int nk = 0; nk < 4; ++nk) {
                float p = __expf(sc[nk][r] - mnew);
                sc[nk][r] = p;
                ls += p;
            }
            ls += __shfl_xor(ls, 1);
            ls += __shfl_xor(ls, 2);
            ls += __shfl_xor(ls, 4);
            ls += __shfl_xor(ls, 8);
            l_i[r] = l_i[r] * alpha + ls;
            m_i[r] = mnew;
#pragma unroll
            for (int nd = 0; nd < 8; ++nd) accO[nd][r] *= alpha;
        }

        // ---- P -> wave-private LDS (swizzled); no barrier needed ----
#pragma unroll
        for (int nk = 0; nk < 4; ++nk)
#pragma unroll
            for (int r = 0; r < 4; ++r) {
                const int row = quad * 4 + r, col = nk * 16 + l16;
                Pw[row * 64 + (((col >> 3) ^ (row & 7)) << 3) + (col & 7)] =
                    (__bf16)sc[nk][r];
            }
        bf16x8 pf[2];
#pragma unroll
        for (int kk = 0; kk < 2; ++kk)
            pf[kk] = *(const bf16x8*)(Pw + l16 * 64 + ((((kk << 2) + quad) ^ swz) << 3));

        // ---- PV: 16 MFMA ----
        __builtin_amdgcn_s_setprio(1);
#pragma unroll
        for (int nd = 0; nd < 8; ++nd)
#pragma unroll
            for (int kk = 0; kk < 2; ++kk) {
                bf16x8 vf = *(const bf16x8*)(Vc + (nd * 16 + l16) * 64 +
                                             ((((kk << 2) + quad) ^ swz) << 3));
                accO[nd] = __builtin_amdgcn_mfma_f32_16x16x32_bf16(pf[kk], vf, accO[nd], 0, 0, 0);
            }
        __builtin_amdgcn_s_setprio(0);
        LGKM0; SCHED0;
        BAR;   // all waves done reading buf(cur); next iter may overwrite it
    }

#pragma unroll
    for (int nd = 0; nd < 8; ++nd)
#pragma unroll
        for (int r = 0; r < 4; ++r) {
            const int s = q0 + wave * 16 + quad * 4 + r;
            const int d = nd * 16 + l16;
            const float o = accO[nd][r] / fmaxf(l_i[r], 1e-20f);
            ctx[((size_t)b * Slen + s) * Hdim + h * HDd + d] = (__bf16)o;
        }
}

extern "C" void kernel_launch(void* const* d_in, const int* in_sizes, int n_in,
                              void* d_out, int out_size, void* d_ws, size_t ws_size,
                              hipStream_t stream) {
    const float* hs   = (const float*)d_in[0];
    const float* wqkv = (const float*)d_in[1];
    const float* bqkv = (const float*)d_in[2];
    const float* wout = (const float*)d_in[3];
    const float* bout = (const float*)d_in[4];
    float* out = (float*)d_out;

    __bf16* ws    = (__bf16*)d_ws;
    __bf16* wqkvT = ws;                          // [6144][2048]
    __bf16* woutT = wqkvT + (size_t)6144 * 2048; // [2048][2048]
    __bf16* Qs    = woutT + (size_t)2048 * 2048; // [B,NH,S,HD] pre-scaled
    __bf16* Kms   = Qs  + (size_t)Bb * NHn * Slen * HDd; // [B,NH,S,HD]
    __bf16* Vts   = Kms + (size_t)Bb * NHn * Slen * HDd; // [B,NH,HD,S]
    __bf16* ctx   = Vts + (size_t)Bb * NHn * Slen * HDd; // [B,S,H] (= hsb)
    __bf16* hsb   = ctx;

    cvt_bf16<<<(Bb * Slen * Hdim) / (256 * 8), 256, 0, stream>>>(hs, hsb);
    transpose_cvt<<<dim3(6144 / 64, 2048 / 64), 256, 0, stream>>>(wqkv, wqkvT, 2048, 6144);
    transpose_cvt<<<dim3(2048 / 64, 2048 / 64), 256, 0, stream>>>(wout, woutT, 2048, 2048);
    gemm8<<<dim3(6144 / 256, 4096 / 256), 512, 0, stream>>>(
        hsb, wqkvT, bqkv, Hdim, 3 * Hdim, Qs, Kms, Vts);
    attn_k<<<dim3(Slen / 128, Bb * NHn), 512, 0, stream>>>(Qs, Kms, Vts, ctx);
    gemm_bm128<<<dim3(2048 / 256, 4096 / 128), 512, 0, stream>>>(
        ctx, woutT, bout, Hdim, Hdim, out);
}

// Round 11
// 416.117 us; speedup vs baseline: 1.0909x; 1.0909x over previous
//
#include <hip/hip_runtime.h>
#include <hip/hip_bf16.h>

typedef __bf16 bf16x8 __attribute__((ext_vector_type(8)));
typedef float  f32x4  __attribute__((ext_vector_type(4)));

constexpr int   Bb   = 2;
constexpr int   Slen = 2048;
constexpr int   Hdim = 2048;
constexpr int   NHn  = 16;
constexpr int   HDd  = 128;
constexpr float QSCALE = 0.08838834764831845f; // 1/sqrt(128)
constexpr float NEG    = -1e30f;

// async global->LDS, 16B per lane; LDS dest = wave-uniform base + lane*16 (m97 pattern)
__device__ __forceinline__ void gld16(const __bf16* g, __bf16* l) {
    __builtin_amdgcn_global_load_lds(
        (__attribute__((address_space(1))) void*)(uintptr_t)(const void*)g,
        (__attribute__((address_space(3))) void*)l, 16, 0, 0);
}

// ---------------- fp32 -> bf16 bulk convert (vectorized) ----------------
__global__ __launch_bounds__(256) void cvt_bf16(const float* __restrict__ in,
                                                __bf16* __restrict__ out) {
    const size_t i = (size_t)(blockIdx.x * 256 + threadIdx.x) * 8;
    f32x4 a = *(const f32x4*)(in + i), b = *(const f32x4*)(in + i + 4);
    bf16x8 r;
    r[0] = (__bf16)a[0]; r[1] = (__bf16)a[1]; r[2] = (__bf16)a[2]; r[3] = (__bf16)a[3];
    r[4] = (__bf16)b[0]; r[5] = (__bf16)b[1]; r[6] = (__bf16)b[2]; r[7] = (__bf16)b[3];
    *(bf16x8*)(out + i) = r;
}

// ---------------- convert+transpose: fp32 [R][C] -> bf16 [C][R] ----------------
__global__ __launch_bounds__(256) void transpose_cvt(const float* __restrict__ in,
                                                     __bf16* __restrict__ out,
                                                     int R, int C) {
    __shared__ float t[64][65];
    const int c0 = blockIdx.x * 64, r0 = blockIdx.y * 64;
    const int tx = threadIdx.x & 63, ty = threadIdx.x >> 6;
#pragma unroll
    for (int i = 0; i < 16; ++i) {
        int r = i * 4 + ty;
        t[r][tx] = in[(size_t)(r0 + r) * C + c0 + tx];
    }
    __syncthreads();
#pragma unroll
    for (int i = 0; i < 16; ++i) {
        int r = i * 4 + ty;
        out[(size_t)(c0 + r) * R + r0 + tx] = (__bf16)t[tx][r];
    }
}

// ============================================================================
// 256x256xBK64 8-phase GEMM — FROZEN (clock canary): 152.9-155.1 us x4 at
// normal clocks; ~194 on a slow container (all rate counters scale together).
// ============================================================================

#define BAR    __builtin_amdgcn_s_barrier()
#define LGKM0  asm volatile("s_waitcnt lgkmcnt(0)" ::: "memory")
#define VMC(n) asm volatile("s_waitcnt vmcnt(" #n ")" ::: "memory")
#define SCHED0 __builtin_amdgcn_sched_barrier(0)

#define STAGE(op, half, tt)                                                          \
  do {                                                                               \
    const int tt_ = (tt);                                                            \
    if (tt_ < NT) {                                                                  \
      __bf16* dst_ = lds + ((tt_ & 1) << 15) + ((op) << 14) + ((half) << 13);        \
      const __bf16* src_ = (op) ? Bt : A;                                            \
      const int rb_ = (op) ? n0 : m0;                                               \
      const int k0_ = tt_ << 6;                                                      \
      _Pragma("unroll")                                                              \
      for (int i_ = 0; i_ < 2; ++i_) {                                               \
        const int c_  = (i_ << 9) + tid;                                             \
        const int rl_ = c_ >> 3;                                                     \
        const int grow_ = rb_ + ((op) ? (((rl_ >> 5) << 6) + ((half) << 5) + (rl_ & 31)) \
                                      : (((rl_ >> 6) << 7) + ((half) << 6) + (rl_ & 63))); \
        const int gk_ = k0_ + (((c_ & 7) ^ (rl_ & 7)) << 3);                         \
        gld16(src_ + (size_t)grow_ * Kdim + gk_, dst_ + (c_ << 3));                  \
      }                                                                              \
    }                                                                                \
  } while (0)

#define LDA(bufv, mh)                                                                \
  do {                                                                               \
    const __bf16* Ab_ = lds + ((bufv) << 15) + ((mh) << 13) + (wg << 12) + (l16 << 6); \
    _Pragma("unroll")                                                                \
    for (int q_ = 0; q_ < 4; ++q_)                                                   \
      _Pragma("unroll")                                                              \
      for (int kk_ = 0; kk_ < 2; ++kk_)                                              \
        af[q_][kk_] = *(const bf16x8*)(Ab_ + (q_ << 10) +                            \
                        ((((kk_ << 2) + quad) ^ (l16 & 7)) << 3));                   \
  } while (0)

#define LDB(bufv, nh)                                                                \
  do {                                                                               \
    const __bf16* Bb_ = lds + ((bufv) << 15) + 16384 + ((nh) << 13) + (gn << 11) + (l16 << 6); \
    _Pragma("unroll")                                                                \
    for (int q_ = 0; q_ < 2; ++q_)                                                   \
      _Pragma("unroll")                                                              \
      for (int kk_ = 0; kk_ < 2; ++kk_)                                              \
        bfr[((nh) << 1) + q_][kk_] = *(const bf16x8*)(Bb_ + (q_ << 10) +             \
                        ((((kk_ << 2) + quad) ^ (l16 & 7)) << 3));                   \
  } while (0)

#define MM(mh, nh)                                                                   \
  do {                                                                               \
    _Pragma("unroll")                                                                \
    for (int q_ = 0; q_ < 4; ++q_)                                                   \
      _Pragma("unroll")                                                              \
      for (int n_ = 0; n_ < 2; ++n_)                                                 \
        _Pragma("unroll")                                                            \
        for (int kk_ = 0; kk_ < 2; ++kk_)                                            \
          acc[((mh) << 2) + q_][((nh) << 1) + n_] =                                  \
            __builtin_amdgcn_mfma_f32_16x16x32_bf16(                                 \
              af[q_][kk_], bfr[((nh) << 1) + n_][kk_],                               \
              acc[((mh) << 2) + q_][((nh) << 1) + n_], 0, 0, 0);                     \
  } while (0)

// QKV epilogue -> scatter Q (scaled), K row-major, V transposed
__global__ __launch_bounds__(512, 2) void gemm8(
    const __bf16* __restrict__ A, const __bf16* __restrict__ Bt,
    const float* __restrict__ bias, int Kdim, int Ndim,
    __bf16* __restrict__ Qo, __bf16* __restrict__ Ko, __bf16* __restrict__ Vto) {
    __shared__ __bf16 lds[65536];  // 128 KiB: [buf][A/B][half][...]
    const int tid  = threadIdx.x;
    const int lane = tid & 63, wave = tid >> 6;
    const int quad = lane >> 4, l16 = lane & 15;
    const int wg = wave >> 2;   // M wave-group (0/1)
    const int gn = wave & 3;    // N wave-group
    const int m0 = blockIdx.y * 256, n0 = blockIdx.x * 256;
    const int NT = Kdim >> 6;

    f32x4  acc[8][4] = {};
    bf16x8 af[4][2];
    bf16x8 bfr[4][2];

    STAGE(0, 0, 0); STAGE(1, 0, 0); STAGE(1, 1, 0); STAGE(0, 1, 0);
    STAGE(0, 0, 1); STAGE(1, 0, 1); STAGE(1, 1, 1);
    VMC(6);
    BAR;

    for (int t = 0; t < NT; ++t) {
        const int cb = t & 1;
        LDA(cb, 0); LDB(cb, 0);
        STAGE(0, 1, t + 1);
        BAR; LGKM0;
        __builtin_amdgcn_s_setprio(1); MM(0, 0); __builtin_amdgcn_s_setprio(0);
        BAR;
        LDB(cb, 1);
        STAGE(0, 0, t + 2);
        BAR; LGKM0;
        __builtin_amdgcn_s_setprio(1); MM(0, 1); __builtin_amdgcn_s_setprio(0);
        BAR;
        LDA(cb, 1);
        STAGE(1, 0, t + 2);
        BAR; LGKM0;
        __builtin_amdgcn_s_setprio(1); MM(1, 1); __builtin_amdgcn_s_setprio(0);
        BAR;
        STAGE(1, 1, t + 2);
        if (t < NT - 2) { VMC(6); } else { VMC(0); }
        BAR;
        __builtin_amdgcn_s_setprio(1); MM(1, 0); __builtin_amdgcn_s_setprio(0);
        BAR;
    }

#pragma unroll
    for (int mi = 0; mi < 8; ++mi) {
#pragma unroll
        for (int r = 0; r < 4; ++r) {
            const int m = m0 + wg * 128 + (mi >> 2) * 64 + (mi & 3) * 16 + quad * 4 + r;
            const int b = m >> 11, s = m & 2047;
#pragma unroll
            for (int ni = 0; ni < 4; ++ni) {
                const int cc = n0 + gn * 64 + (ni >> 1) * 32 + (ni & 1) * 16 + l16;
                float val = acc[mi][ni][r] + bias[cc];
                const int h = cc / 384;
                const int rr = cc - h * 384;
                const size_t hb = ((size_t)(b * NHn + h) * Slen + s);
                if (rr < 128)
                    Qo[hb * HDd + rr] = (__bf16)(val * QSCALE);
                else if (rr < 256)
                    Ko[hb * HDd + (rr - 128)] = (__bf16)val;
                else
                    Vto[((size_t)(b * NHn + h) * HDd + (rr - 256)) * Slen + s] = (__bf16)val;
            }
        }
    }
}

// ============================================================================
// Output-projection GEMM — FROZEN: BM=128 x BN=256 x BK=64, 8 waves of 64x64,
// 4-phase counted-vmcnt, no pins, 256 blocks (full chip).
// ============================================================================

#define STA1(half, tt)                                                               \
  do {                                                                               \
    const int tt_ = (tt);                                                            \
    if (tt_ < NT) {                                                                  \
      __bf16* dst_ = lds2 + ((tt_ & 1) ? 24576 : 0) + ((half) << 12);                \
      const int k0_ = tt_ << 6;                                                      \
      const int c_  = tid;                       /* 0..511, 1 chunk each */          \
      const int rl_ = c_ >> 3;                   /* 0..63 local A-half row */        \
      const int grow_ = m0 + ((rl_ >> 5) << 6) + ((half) << 5) + (rl_ & 31);         \
      const int gk_ = k0_ + (((c_ & 7) ^ (rl_ & 7)) << 3);                           \
      gld16(A + (size_t)grow_ * Kdim + gk_, dst_ + (c_ << 3));                       \
    }                                                                                \
  } while (0)

#define STB1(half, tt)                                                               \
  do {                                                                               \
    const int tt_ = (tt);                                                            \
    if (tt_ < NT) {                                                                  \
      __bf16* dst_ = lds2 + ((tt_ & 1) ? 24576 : 0) + 8192 + ((half) << 13);         \
      const int k0_ = tt_ << 6;                                                      \
      _Pragma("unroll")                                                              \
      for (int i_ = 0; i_ < 2; ++i_) {                                               \
        const int c_  = (i_ << 9) + tid;         /* 0..1023 */                       \
        const int rl_ = c_ >> 3;                 /* 0..127 local B-half row */       \
        const int grow_ = n0 + ((rl_ >> 5) << 6) + ((half) << 5) + (rl_ & 31);       \
        const int gk_ = k0_ + (((c_ & 7) ^ (rl_ & 7)) << 3);                         \
        gld16(Bt + (size_t)grow_ * Kdim + gk_, dst_ + (c_ << 3));                    \
      }                                                                              \
    }                                                                                \
  } while (0)

#define LDA1(bufv, h)                                                                \
  do {                                                                               \
    const __bf16* Ab_ = lds2 + ((bufv) ? 24576 : 0) + ((h) << 12) + (wg << 11) + (l16 << 6); \
    _Pragma("unroll")                                                                \
    for (int q_ = 0; q_ < 2; ++q_)                                                   \
      _Pragma("unroll")                                                              \
      for (int kk_ = 0; kk_ < 2; ++kk_)                                              \
        af1[q_][kk_] = *(const bf16x8*)(Ab_ + (q_ << 10) +                           \
                        ((((kk_ << 2) + quad) ^ (l16 & 7)) << 3));                   \
  } while (0)

#define LDB1(bufv, nh)                                                               \
  do {                                                                               \
    const __bf16* Bb_ = lds2 + ((bufv) ? 24576 : 0) + 8192 + ((nh) << 13) + (gn << 11) + (l16 << 6); \
    _Pragma("unroll")                                                                \
    for (int q_ = 0; q_ < 2; ++q_)                                                   \
      _Pragma("unroll")                                                              \
      for (int kk_ = 0; kk_ < 2; ++kk_)                                              \
        bfr1[((nh) << 1) + q_][kk_] = *(const bf16x8*)(Bb_ + (q_ << 10) +            \
                        ((((kk_ << 2) + quad) ^ (l16 & 7)) << 3));                   \
  } while (0)

#define MM1(h, nh)                                                                   \
  do {                                                                               \
    _Pragma("unroll")                                                                \
    for (int q_ = 0; q_ < 2; ++q_)                                                   \
      _Pragma("unroll")                                                              \
      for (int n_ = 0; n_ < 2; ++n_)                                                 \
        _Pragma("unroll")                                                            \
        for (int kk_ = 0; kk_ < 2; ++kk_)                                            \
          acc1[((h) << 1) + q_][((nh) << 1) + n_] =                                  \
            __builtin_amdgcn_mfma_f32_16x16x32_bf16(                                 \
              af1[q_][kk_], bfr1[((nh) << 1) + n_][kk_],                             \
              acc1[((h) << 1) + q_][((nh) << 1) + n_], 0, 0, 0);                     \
  } while (0)

__global__ __launch_bounds__(512, 2) void gemm_bm128(
    const __bf16* __restrict__ A, const __bf16* __restrict__ Bt,
    const float* __restrict__ bias, int Kdim, int Ndim,
    float* __restrict__ Cout) {
    __shared__ __bf16 lds2[49152];  // 96 KiB: 2 x (A 8192 + B 16384 elems)
    const int tid  = threadIdx.x;
    const int lane = tid & 63, wave = tid >> 6;
    const int quad = lane >> 4, l16 = lane & 15;
    const int wg = wave >> 2;   // M wave-group (0/1) -> rows wg*64..+63
    const int gn = wave & 3;    // N wave-group      -> cols gn*64..+63
    const int m0 = blockIdx.y * 128, n0 = blockIdx.x * 256;
    const int NT = Kdim >> 6;

    f32x4  acc1[4][4] = {};
    bf16x8 af1[2][2];
    bf16x8 bfr1[4][2];

    STA1(0, 0); STB1(0, 0); STB1(1, 0); STA1(1, 0);
    STA1(0, 1); STB1(0, 1); STB1(1, 1);
    VMC(5);
    BAR;

    for (int t = 0; t < NT; ++t) {
        const int cb = t & 1;
        LDA1(cb, 0); LDB1(cb, 0);
        STA1(1, t + 1);
        BAR; LGKM0;
        __builtin_amdgcn_s_setprio(1); MM1(0, 0); __builtin_amdgcn_s_setprio(0);
        BAR;
        LDB1(cb, 1);
        STA1(0, t + 2);
        BAR; LGKM0;
        __builtin_amdgcn_s_setprio(1); MM1(0, 1); __builtin_amdgcn_s_setprio(0);
        BAR;
        LDA1(cb, 1);
        STB1(0, t + 2);
        BAR; LGKM0;
        __builtin_amdgcn_s_setprio(1); MM1(1, 1); __builtin_amdgcn_s_setprio(0);
        BAR;
        STB1(1, t + 2);
        if (t < NT - 2) { VMC(5); } else { VMC(0); }
        BAR;
        __builtin_amdgcn_s_setprio(1); MM1(1, 0); __builtin_amdgcn_s_setprio(0);
        BAR;
    }

#pragma unroll
    for (int mi = 0; mi < 4; ++mi) {
#pragma unroll
        for (int r = 0; r < 4; ++r) {
            const int m = m0 + wg * 64 + (mi >> 1) * 32 + (mi & 1) * 16 + quad * 4 + r;
#pragma unroll
            for (int ni = 0; ni < 4; ++ni) {
                const int cc = n0 + gn * 64 + (ni >> 1) * 32 + (ni & 1) * 16 + l16;
                Cout[(size_t)m * Ndim + cc] = acc1[mi][ni][r] + bias[cc];
            }
        }
    }
}

// ============================================================================
// flash attention — COMP-MAP restored (both ~420 us totals used this map;
// r3-grouped map runs measured rest +80 us at normal clocks). Each CU's two
// resident blocks get complementary qt (u, 15-u) under either HW pairing ->
// constant 34-tile per-CU makespan. Softmax/pins byte-identical to r5/r7.
// ============================================================================

#define ASTAGE(tt)                                                                   \
  do {                                                                               \
    const int tt_ = (tt);                                                            \
    if (tt_ < ktiles) {                                                              \
      const int kb_ = tt_ << 6;                                                      \
      __bf16* kd_ = Ks + ((tt_ & 1) << 13);                                          \
      __bf16* vd_ = Vs + ((tt_ & 1) << 13);                                          \
      _Pragma("unroll")                                                              \
      for (int i_ = 0; i_ < 2; ++i_) {                                               \
        const int c_ = (i_ << 9) + tid;              /* 0..1023 chunk id */          \
        const int kr_ = c_ >> 4, kc_ = c_ & 15;      /* K: row=key, 16 chunks */     \
        gld16(Kb + (size_t)(kb_ + kr_) * HDd + ((kc_ ^ (kr_ & 7)) << 3),             \
              kd_ + (c_ << 3));                                                      \
        const int vr_ = c_ >> 3, vc_ = c_ & 7;       /* V: row=d, 8 chunks */        \
        gld16(Vb + (size_t)vr_ * Slen + kb_ + ((vc_ ^ (vr_ & 7)) << 3),              \
              vd_ + (c_ << 3));                                                      \
      }                                                                              \
    }                                                                                \
  } while (0)

__global__ __launch_bounds__(512, 4) void attn_k(const __bf16* __restrict__ Q,
                                                 const __bf16* __restrict__ Kmat,
                                                 const __bf16* __restrict__ Vt,
                                                 __bf16* __restrict__ ctx) {
    __shared__ __bf16 Ks[2 * 64 * 128];   // 32KB dbuf [key][d]
    __shared__ __bf16 Vs[2 * 128 * 64];   // 32KB dbuf [d][key]
    __shared__ __bf16 Ps[8 * 16 * 64];    // 16KB wave-private P, swizzled
    const int tid = threadIdx.x, lane = tid & 63, wave = tid >> 6;
    const int quad = lane >> 4, l16 = lane & 15;

    // work-balanced XCD-local remap (qt complements under either HW pairing)
    const int flat = blockIdx.x + (blockIdx.y << 4);   // 0..511, gridDim.x == 16
    const int x    = flat & 7;                          // XCD (round-robin heuristic)
    const int k    = flat >> 3;                         // 0..63 within XCD
    const int u    = (k >> 1) & 15;
    const int s_   = (k ^ (k >> 5)) & 1;
    const int qt   = s_ ? (15 - u) : u;
    const int bh   = x * 4 + (k & 1) + ((k >> 5) << 1); // 4 bh per XCD (KV L2 locality)
    const int b = bh >> 4, h = bh & 15;
    const __bf16* Qb = Q    + (size_t)bh * Slen * HDd;
    const __bf16* Kb = Kmat + (size_t)bh * Slen * HDd;
    const __bf16* Vb = Vt   + (size_t)bh * HDd * Slen;
    const int q0 = qt * 128;
    const int qa = q0 + wave * 16 + l16;       // A-frag row
    const int qc = q0 + wave * 16 + quad * 4;  // C-layout base row
    const int swz = (l16 & 7);

    bf16x8 qf[4];
#pragma unroll
    for (int kk = 0; kk < 4; ++kk)
        qf[kk] = *(const bf16x8*)(Qb + (size_t)qa * HDd + kk * 32 + quad * 8);

    f32x4 accO[8] = {};
    float m_i[4] = {NEG, NEG, NEG, NEG};
    float l_i[4] = {0.f, 0.f, 0.f, 0.f};
    __bf16* Pw = Ps + wave * 1024;  // [16 rows][64 cols], chunk-swizzled

    const int ktiles = 2 * qt + 2;  // 64-key tiles covering keys 0..q0+127

    ASTAGE(0);
    for (int kt = 0; kt < ktiles; ++kt) {
        const int cur = kt & 1;
        const int kb0 = kt * 64;
        ASTAGE(kt + 1);                       // prefetch next tile into ~cur
        SCHED0;
        if (kt + 1 < ktiles) { VMC(4); } else { VMC(0); }
        BAR;                                  // buf(cur) staged by ALL waves

        const __bf16* Kt = Ks + (cur << 13);
        const __bf16* Vc = Vs + (cur << 13);

        // ---- QK^T: 16 MFMA ----
        f32x4 sc[4];
        __builtin_amdgcn_s_setprio(1);
#pragma unroll
        for (int nk = 0; nk < 4; ++nk) {
            f32x4 z = {0.f, 0.f, 0.f, 0.f};
#pragma unroll
            for (int kk = 0; kk < 4; ++kk) {
                bf16x8 kf = *(const bf16x8*)(Kt + (nk * 16 + l16) * 128 +
                                             (((kk << 2) + quad) ^ swz) * 8);
                z = __builtin_amdgcn_mfma_f32_16x16x32_bf16(qf[kk], kf, z, 0, 0, 0);
            }
            sc[nk] = z;
        }
        __builtin_amdgcn_s_setprio(0);
        if (kt >= ktiles - 2) {  // diagonal-range tiles: causal mask
#pragma unroll
            for (int nk = 0; nk < 4; ++nk) {
                const int kg = kb0 + nk * 16 + l16;
#pragma unroll
                for (int r = 0; r < 4; ++r)
                    if (kg > qc + r) sc[nk][r] = NEG;
            }
        }
        // ---- online softmax across the quad's 16 lanes ----
#pragma unroll
        for (int r = 0; r < 4; ++r) {
            float mm = fmaxf(fmaxf(sc[0][r], sc[1][r]), fmaxf(sc[2][r], sc[3][r]));
            mm = fmaxf(mm, __shfl_xor(mm, 1));
            mm = fmaxf(mm, __shfl_xor(mm, 2));
            mm = fmaxf(mm, __shfl_xor(mm, 4));
            mm = fmaxf(mm, __shfl_xor(mm, 8));
            const float mnew = fmaxf(m_i[r], mm);
            const float alpha = __expf(m_i[r] - mnew);
            float ls = 0.f;
#pragma unroll
            for (int nk = 0; nk < 4; ++nk) {
                float p = __expf(sc[nk][r] - mnew);
                sc[nk][r] = p;
                ls += p;
            }
            ls += __shfl_xor(ls, 1);
            ls += __shfl_xor(ls, 2);
            ls += __shfl_xor(ls, 4);
            ls += __shfl_xor(ls, 8);
            l_i[r] = l_i[r] * alpha + ls;
            m_i[r] = mnew;
#pragma unroll
            for (int nd = 0; nd < 8; ++nd) accO[nd][r] *= alpha;
        }

        // ---- P -> wave-private LDS (swizzled); no barrier needed ----
#pragma unroll
        for (int nk = 0; nk < 4; ++nk)
#pragma unroll
            for (int r = 0; r < 4; ++r) {
                const int row = quad * 4 + r, col = nk * 16 + l16;
                Pw[row * 64 + (((col >> 3) ^ (row & 7)) << 3) + (col & 7)] =
                    (__bf16)sc[nk][r];
            }
        bf16x8 pf[2];
#pragma unroll
        for (int kk = 0; kk < 2; ++kk)
            pf[kk] = *(const bf16x8*)(Pw + l16 * 64 + ((((kk << 2) + quad) ^ swz) << 3));

        // ---- PV: 16 MFMA ----
        __builtin_amdgcn_s_setprio(1);
#pragma unroll
        for (int nd = 0; nd < 8; ++nd)
#pragma unroll
            for (int kk = 0; kk < 2; ++kk) {
                bf16x8 vf = *(const bf16x8*)(Vc + (nd * 16 + l16) * 64 +
                                             ((((kk << 2) + quad) ^ swz) << 3));
                accO[nd] = __builtin_amdgcn_mfma_f32_16x16x32_bf16(pf[kk], vf, accO[nd], 0, 0, 0);
            }
        __builtin_amdgcn_s_setprio(0);
        LGKM0; SCHED0;
        BAR;   // all waves done reading buf(cur); next iter may overwrite it
    }

#pragma unroll
    for (int nd = 0; nd < 8; ++nd)
#pragma unroll
        for (int r = 0; r < 4; ++r) {
            const int s = q0 + wave * 16 + quad * 4 + r;
            const int d = nd * 16 + l16;
            const float o = accO[nd][r] / fmaxf(l_i[r], 1e-20f);
            ctx[((size_t)b * Slen + s) * Hdim + h * HDd + d] = (__bf16)o;
        }
}

extern "C" void kernel_launch(void* const* d_in, const int* in_sizes, int n_in,
                              void* d_out, int out_size, void* d_ws, size_t ws_size,
                              hipStream_t stream) {
    const float* hs   = (const float*)d_in[0];
    const float* wqkv = (const float*)d_in[1];
    const float* bqkv = (const float*)d_in[2];
    const float* wout = (const float*)d_in[3];
    const float* bout = (const float*)d_in[4];
    float* out = (float*)d_out;

    __bf16* ws    = (__bf16*)d_ws;
    __bf16* wqkvT = ws;                          // [6144][2048]
    __bf16* woutT = wqkvT + (size_t)6144 * 2048; // [2048][2048]
    __bf16* Qs    = woutT + (size_t)2048 * 2048; // [B,NH,S,HD] pre-scaled
    __bf16* Kms   = Qs  + (size_t)Bb * NHn * Slen * HDd; // [B,NH,S,HD]
    __bf16* Vts   = Kms + (size_t)Bb * NHn * Slen * HDd; // [B,NH,HD,S]
    __bf16* ctx   = Vts + (size_t)Bb * NHn * Slen * HDd; // [B,S,H] (= hsb)
    __bf16* hsb   = ctx;

    cvt_bf16<<<(Bb * Slen * Hdim) / (256 * 8), 256, 0, stream>>>(hs, hsb);
    transpose_cvt<<<dim3(6144 / 64, 2048 / 64), 256, 0, stream>>>(wqkv, wqkvT, 2048, 6144);
    transpose_cvt<<<dim3(2048 / 64, 2048 / 64), 256, 0, stream>>>(wout, woutT, 2048, 2048);
    gemm8<<<dim3(6144 / 256, 4096 / 256), 512, 0, stream>>>(
        hsb, wqkvT, bqkv, Hdim, 3 * Hdim, Qs, Kms, Vts);
    attn_k<<<dim3(Slen / 128, Bb * NHn), 512, 0, stream>>>(Qs, Kms, Vts, ctx);
    gemm_bm128<<<dim3(2048 / 256, 4096 / 128), 512, 0, stream>>>(
        ctx, woutT, bout, Hdim, Hdim, out);
}